// Round 1
// baseline (61.362 us; speedup 1.0000x reference)
//
#include <hip/hip_runtime.h>
#include <hip/hip_bf16.h>

typedef __attribute__((ext_vector_type(8))) short bf16x8;
typedef __attribute__((ext_vector_type(4))) float f32x4;

#define BATCH 16
#define SEQ   1024
#define EMB   768
#define HEAD  64
#define NT    (BATCH*SEQ)

__device__ inline ushort f2bf(float f) {
  __hip_bfloat16 h = __float2bfloat16(f);
  return *reinterpret_cast<const ushort*>(&h);
}

// ---------------- QKV projection: C[t,h] = sum_d x[t,d] * W[h,d] ----------------
// grid (NT/64, 3): blockIdx.y selects Wq/Wk/Wv. 256 threads = 4 waves.
// Wave w computes rows 16w..16w+15 x all 64 cols (4 fragments).
__global__ __launch_bounds__(256) void proj_kernel(
    const float* __restrict__ x,  const float* __restrict__ Wq,
    const float* __restrict__ Wk, const float* __restrict__ Wv,
    ushort* __restrict__ qo, ushort* __restrict__ ko, ushort* __restrict__ vo)
{
  __shared__ ushort lx[64][40];   // 64 rows x (32 + 8 pad), 16B-aligned rows
  __shared__ ushort lw[64][40];

  const int tid  = threadIdx.x;
  const int m0   = blockIdx.x * 64;
  const int sel  = blockIdx.y;
  const float* W = (sel == 0) ? Wq : (sel == 1 ? Wk : Wv);

  const int wave = tid >> 6, lane = tid & 63;
  const int srow = tid >> 2, scol = (tid & 3) * 8;     // staging: row, 8-float chunk
  const int arow = 16 * wave + (lane & 15);
  const int koff = (lane >> 4) * 8;

  f32x4 acc[4];
  #pragma unroll
  for (int f = 0; f < 4; ++f) acc[f] = (f32x4){0.f, 0.f, 0.f, 0.f};

  for (int k0 = 0; k0 < EMB; k0 += 32) {
    // ---- stage x-tile and W-tile (fp32 -> bf16) ----
    {
      const float4 a0 = *reinterpret_cast<const float4*>(&x[(size_t)(m0 + srow) * EMB + k0 + scol]);
      const float4 a1 = *reinterpret_cast<const float4*>(&x[(size_t)(m0 + srow) * EMB + k0 + scol + 4]);
      union { ushort us[8]; uint4 u4; } t;
      t.us[0]=f2bf(a0.x); t.us[1]=f2bf(a0.y); t.us[2]=f2bf(a0.z); t.us[3]=f2bf(a0.w);
      t.us[4]=f2bf(a1.x); t.us[5]=f2bf(a1.y); t.us[6]=f2bf(a1.z); t.us[7]=f2bf(a1.w);
      *reinterpret_cast<uint4*>(&lx[srow][scol]) = t.u4;

      const float4 b0 = *reinterpret_cast<const float4*>(&W[(size_t)srow * EMB + k0 + scol]);
      const float4 b1 = *reinterpret_cast<const float4*>(&W[(size_t)srow * EMB + k0 + scol + 4]);
      union { ushort us[8]; uint4 u4; } u;
      u.us[0]=f2bf(b0.x); u.us[1]=f2bf(b0.y); u.us[2]=f2bf(b0.z); u.us[3]=f2bf(b0.w);
      u.us[4]=f2bf(b1.x); u.us[5]=f2bf(b1.y); u.us[6]=f2bf(b1.z); u.us[7]=f2bf(b1.w);
      *reinterpret_cast<uint4*>(&lw[srow][scol]) = u.u4;
    }
    __syncthreads();
    const bf16x8 a = *reinterpret_cast<const bf16x8*>(&lx[arow][koff]);
    #pragma unroll
    for (int f = 0; f < 4; ++f) {
      const bf16x8 b = *reinterpret_cast<const bf16x8*>(&lw[16 * f + (lane & 15)][koff]);
      acc[f] = __builtin_amdgcn_mfma_f32_16x16x32_bf16(a, b, acc[f], 0, 0, 0);
    }
    __syncthreads();
  }

  // ---- epilogue: D layout col = lane&15, row = (lane>>4)*4 + i ----
  const int r0 = (lane >> 4) * 4;
  #pragma unroll
  for (int f = 0; f < 4; ++f) {
    const int n = 16 * f + (lane & 15);
    #pragma unroll
    for (int i = 0; i < 4; ++i) {
      const int t = m0 + 16 * wave + r0 + i;
      const ushort val = f2bf(acc[f][i]);
      if (sel == 0)       qo[(size_t)t * HEAD + n] = val;
      else if (sel == 1)  ko[(size_t)t * HEAD + n] = val;
      else {  // V stored transposed: vT[b][h][t_in_batch]
        const int bb = t >> 10, tin = t & 1023;
        vo[((size_t)bb * HEAD + n) * SEQ + tin] = val;
      }
    }
  }
}

// ---------------- Flash attention: one block per (batch, 64-row Q tile) ----------------
__global__ __launch_bounds__(256) void attn_kernel(
    const ushort* __restrict__ q, const ushort* __restrict__ k,
    const ushort* __restrict__ vT, float* __restrict__ out)
{
  __shared__ ushort lk[64][72];        // K tile [kv][h], padded
  __shared__ ushort lv[64][72];        // V tile [h][kv] (from vT), padded
  __shared__ ushort lp[4][16][72];     // per-wave P re-layout buffer

  const int tid  = threadIdx.x;
  const int wave = tid >> 6, lane = tid & 63;
  const int b    = blockIdx.y;
  const int qt0  = blockIdx.x * 64;
  const float scale = 0.03608439182435161f;   // 768^-0.5
  const float LOG2E = 1.4426950408889634f;

  const int koff = (lane >> 4) * 8;

  // Q fragments in registers (A-layout: row = lane&15, k = koff + j)
  const int qrow = qt0 + 16 * wave + (lane & 15);
  const bf16x8 qa0 = *reinterpret_cast<const bf16x8*>(&q[((size_t)b * SEQ + qrow) * HEAD + koff]);
  const bf16x8 qa1 = *reinterpret_cast<const bf16x8*>(&q[((size_t)b * SEQ + qrow) * HEAD + koff + 32]);

  f32x4 o[4];
  #pragma unroll
  for (int hf = 0; hf < 4; ++hf) o[hf] = (f32x4){0.f, 0.f, 0.f, 0.f};
  float m_run[4], l_run[4];
  #pragma unroll
  for (int i = 0; i < 4; ++i) { m_run[i] = -1e30f; l_run[i] = 0.f; }

  const int srow = tid >> 2, schunk = (tid & 3) * 16;   // staging coords
  const int ntiles = qt0 / 64 + 1;                       // causal: tiles 0..qt0/64

  for (int kt = 0; kt < ntiles; ++kt) {
    const int kv0 = kt * 64;
    __syncthreads();   // protect lk/lv from previous iteration's readers
    // ---- stage K tile [kv][h] and V tile [h][kv] ----
    {
      const uint4* sk = reinterpret_cast<const uint4*>(&k[((size_t)b * SEQ + kv0 + srow) * HEAD + schunk]);
      uint4 k0v = sk[0], k1v = sk[1];
      *reinterpret_cast<uint4*>(&lk[srow][schunk])     = k0v;
      *reinterpret_cast<uint4*>(&lk[srow][schunk + 8]) = k1v;
      const uint4* sv = reinterpret_cast<const uint4*>(&vT[((size_t)b * HEAD + srow) * SEQ + kv0 + schunk]);
      uint4 v0v = sv[0], v1v = sv[1];
      *reinterpret_cast<uint4*>(&lv[srow][schunk])     = v0v;
      *reinterpret_cast<uint4*>(&lv[srow][schunk + 8]) = v1v;
    }
    __syncthreads();

    // ---- S = Q * K^T (scaled later): 4 column-fragments of 16x16 ----
    f32x4 s[4];
    #pragma unroll
    for (int f = 0; f < 4; ++f) {
      const bf16x8 kb0 = *reinterpret_cast<const bf16x8*>(&lk[16 * f + (lane & 15)][koff]);
      const bf16x8 kb1 = *reinterpret_cast<const bf16x8*>(&lk[16 * f + (lane & 15)][koff + 32]);
      f32x4 z = (f32x4){0.f, 0.f, 0.f, 0.f};
      z    = __builtin_amdgcn_mfma_f32_16x16x32_bf16(qa0, kb0, z, 0, 0, 0);
      s[f] = __builtin_amdgcn_mfma_f32_16x16x32_bf16(qa1, kb1, z, 0, 0, 0);
    }

    // ---- scale + causal mask (only diagonal tile needs mask) ----
    const bool diag = (kv0 == qt0);
    float pv[4][4];    // [f][i]
    float mx[4];
    #pragma unroll
    for (int i = 0; i < 4; ++i) mx[i] = -1e30f;
    #pragma unroll
    for (int f = 0; f < 4; ++f) {
      const int kvc = 16 * f + (lane & 15);
      #pragma unroll
      for (int i = 0; i < 4; ++i) {
        float val = s[f][i] * scale;
        if (diag) {
          const int qr = 16 * wave + (lane >> 4) * 4 + i;
          if (kvc > qr) val = -1e30f;
        }
        pv[f][i] = val;
        mx[i] = fmaxf(mx[i], val);
      }
    }
    // row-max across the 16 lanes holding this row's columns
    #pragma unroll
    for (int i = 0; i < 4; ++i) {
      #pragma unroll
      for (int d = 1; d < 16; d <<= 1) mx[i] = fmaxf(mx[i], __shfl_xor(mx[i], d));
    }

    // ---- online softmax update ----
    #pragma unroll
    for (int i = 0; i < 4; ++i) {
      const float mnew = fmaxf(m_run[i], mx[i]);
      const float resc = exp2f((m_run[i] - mnew) * LOG2E);
      m_run[i] = mnew;
      l_run[i] *= resc;
      #pragma unroll
      for (int hf = 0; hf < 4; ++hf) o[hf][i] *= resc;
      float rs = 0.f;
      #pragma unroll
      for (int f = 0; f < 4; ++f) {
        const float p = exp2f((pv[f][i] - mnew) * LOG2E);
        pv[f][i] = p;
        rs += p;
      }
      #pragma unroll
      for (int d = 1; d < 16; d <<= 1) rs += __shfl_xor(rs, d);
      l_run[i] += rs;
    }

    // ---- P -> LDS (re-layout to A-fragment), then PV ----
    #pragma unroll
    for (int f = 0; f < 4; ++f) {
      #pragma unroll
      for (int i = 0; i < 4; ++i)
        lp[wave][(lane >> 4) * 4 + i][16 * f + (lane & 15)] = f2bf(pv[f][i]);
    }
    const bf16x8 pa0 = *reinterpret_cast<const bf16x8*>(&lp[wave][lane & 15][koff]);
    const bf16x8 pa1 = *reinterpret_cast<const bf16x8*>(&lp[wave][lane & 15][koff + 32]);
    #pragma unroll
    for (int hf = 0; hf < 4; ++hf) {
      const bf16x8 vb0 = *reinterpret_cast<const bf16x8*>(&lv[16 * hf + (lane & 15)][koff]);
      const bf16x8 vb1 = *reinterpret_cast<const bf16x8*>(&lv[16 * hf + (lane & 15)][koff + 32]);
      o[hf] = __builtin_amdgcn_mfma_f32_16x16x32_bf16(pa0, vb0, o[hf], 0, 0, 0);
      o[hf] = __builtin_amdgcn_mfma_f32_16x16x32_bf16(pa1, vb1, o[hf], 0, 0, 0);
    }
  }

  // ---- epilogue: out = o / l ----
  #pragma unroll
  for (int i = 0; i < 4; ++i) {
    const float inv = 1.0f / l_run[i];
    const int t = qt0 + 16 * wave + (lane >> 4) * 4 + i;
    #pragma unroll
    for (int hf = 0; hf < 4; ++hf) {
      out[((size_t)b * SEQ + t) * HEAD + 16 * hf + (lane & 15)] = o[hf][i] * inv;
    }
  }
}

extern "C" void kernel_launch(void* const* d_in, const int* in_sizes, int n_in,
                              void* d_out, int out_size, void* d_ws, size_t ws_size,
                              hipStream_t stream) {
  const float* x  = (const float*)d_in[0];
  const float* Wq = (const float*)d_in[1];
  const float* Wk = (const float*)d_in[2];
  const float* Wv = (const float*)d_in[3];

  ushort* qw  = (ushort*)d_ws;                 // [NT][64] bf16
  ushort* kw  = qw + (size_t)NT * HEAD;        // [NT][64] bf16
  ushort* vTw = kw + (size_t)NT * HEAD;        // [B][64][1024] bf16
  float*  out = (float*)d_out;

  dim3 pg(NT / 64, 3);
  proj_kernel<<<pg, 256, 0, stream>>>(x, Wq, Wk, Wv, qw, kw, vTw);

  dim3 ag(SEQ / 64, BATCH);
  attn_kernel<<<ag, 256, 0, stream>>>(qw, kw, vTw, out);
}

// Round 2
// 60.576 us; speedup vs baseline: 1.0130x; 1.0130x over previous
//
#include <hip/hip_runtime.h>
#include <hip/hip_bf16.h>

typedef __attribute__((ext_vector_type(8))) short bf16x8;
typedef __attribute__((ext_vector_type(4))) float f32x4;

#define BATCH 16
#define SEQ   1024
#define EMB   768
#define HEAD  64
#define NT    (BATCH*SEQ)
#define NQKV  192            // 3*64 fused output cols
#define BK    128            // K-chunk
#define LXS   136            // lx row stride (elems): 272B rows -> 2-way free

__device__ inline ushort f2bf(float f) {
  __hip_bfloat16 h = __float2bfloat16(f);
  return *reinterpret_cast<const ushort*>(&h);
}

__device__ inline void lds_dma16(const void* g, void* l) {
  __builtin_amdgcn_global_load_lds(
      (const __attribute__((address_space(1))) void*)g,
      (__attribute__((address_space(3))) void*)l, 16, 0, 0);
}

// ---------- W fp32 -> bf16, pre-swizzled for linear global_load_lds ----------
// wt[row][chunk*128 + g*8 + e] = W[row][chunk*128 + (g^(row&7))*8 + e]
// so that a linear DMA of a 128-col chunk gives LDS whose ds_read applies g^=row&7.
__global__ __launch_bounds__(256) void convw_kernel(
    const float* __restrict__ Wq, const float* __restrict__ Wk,
    const float* __restrict__ Wv, ushort* __restrict__ wt)
{
  const int t = blockIdx.x * 256 + threadIdx.x;     // 192 rows * 96 groups
  const int row = t / 96;
  const int gg  = t - row * 96;                     // 8-elem group within row
  const int chunk = gg >> 4, g = gg & 15;
  const int gsrc = (g ^ (row & 7)) + chunk * 16;
  const float* W = (row < 64) ? Wq : (row < 128 ? Wk : Wv);
  const int r = row & 63;
  const float4 f0 = *reinterpret_cast<const float4*>(&W[(size_t)r * EMB + gsrc * 8]);
  const float4 f1 = *reinterpret_cast<const float4*>(&W[(size_t)r * EMB + gsrc * 8 + 4]);
  union { ushort us[8]; uint4 u; } o;
  o.us[0]=f2bf(f0.x); o.us[1]=f2bf(f0.y); o.us[2]=f2bf(f0.z); o.us[3]=f2bf(f0.w);
  o.us[4]=f2bf(f1.x); o.us[5]=f2bf(f1.y); o.us[6]=f2bf(f1.z); o.us[7]=f2bf(f1.w);
  *reinterpret_cast<uint4*>(&wt[(size_t)row * EMB + gg * 8]) = o.u;
}

// ---------- fused QKV projection ----------
// grid 256 blocks x 256 thr (4 waves). Block: M=64 rows, N=192 (q|k|v), BK=128.
// Wave w: all 64 rows x cols [48w, 48w+48) = 4 Mfrag x 3 Nfrag.
__global__ __launch_bounds__(256) void proj_kernel(
    const float* __restrict__ x, const ushort* __restrict__ wt,
    ushort* __restrict__ qo, ushort* __restrict__ ko, ushort* __restrict__ vo)
{
  __shared__ ushort lw[2][NQKV * BK];     // double-buffered, swizzled content, linear rows (256B)
  __shared__ ushort lx[64 * LXS];

  const int tid  = threadIdx.x;
  const int wave = tid >> 6, lane = tid & 63;
  const int m0   = blockIdx.x * 64;
  const int koff = (lane >> 4) * 8;

  // ---- x prefetch regs: 8 x float4 per thread ----
  const int xrow0 = tid >> 5;            // + 8j
  const int xc4   = (tid & 31) * 4;
  float4 xr[8];

  #define LOAD_X(k0_)                                                          \
    { _Pragma("unroll")                                                        \
      for (int j = 0; j < 8; ++j)                                              \
        xr[j] = *reinterpret_cast<const float4*>(                              \
            &x[(size_t)(m0 + xrow0 + 8 * j) * EMB + (k0_) + xc4]); }

  #define WRITE_LX()                                                           \
    { _Pragma("unroll")                                                        \
      for (int j = 0; j < 8; ++j) {                                            \
        uint2 o;                                                               \
        o.x = (uint)f2bf(xr[j].x) | ((uint)f2bf(xr[j].y) << 16);               \
        o.y = (uint)f2bf(xr[j].z) | ((uint)f2bf(xr[j].w) << 16);               \
        *reinterpret_cast<uint2*>(&lx[(xrow0 + 8 * j) * LXS + xc4]) = o;       \
      } }

  // ---- W DMA: wave stages rows [48w, 48w+48), 12 calls x 1KB ----
  #define STAGE_W(k0_, buf_)                                                   \
    { const int rb = wave * 48;                                                \
      _Pragma("unroll")                                                        \
      for (int c = 0; c < 12; ++c) {                                           \
        const int row = rb + c * 4 + (lane >> 4);                              \
        lds_dma16(&wt[(size_t)row * EMB + (k0_) + (lane & 15) * 8],            \
                  &lw[buf_][(rb + c * 4) * BK]);                               \
      } }

  f32x4 acc[4][3];
  #pragma unroll
  for (int m = 0; m < 4; ++m)
    #pragma unroll
    for (int n = 0; n < 3; ++n) acc[m][n] = (f32x4){0.f, 0.f, 0.f, 0.f};

  // prologue
  STAGE_W(0, 0);
  LOAD_X(0);

  const int bn0 = wave * 48;
  for (int kt = 0; kt < 6; ++kt) {
    const int cur = kt & 1;
    WRITE_LX();
    __syncthreads();                       // lx + lw[cur] ready (vmcnt drain)
    if (kt < 5) {
      STAGE_W((kt + 1) * BK, cur ^ 1);     // overlaps MFMA phase
      LOAD_X((kt + 1) * BK);
    }
    #pragma unroll
    for (int ks = 0; ks < 4; ++ks) {
      bf16x8 a[4];
      #pragma unroll
      for (int m = 0; m < 4; ++m)
        a[m] = *reinterpret_cast<const bf16x8*>(
            &lx[(16 * m + (lane & 15)) * LXS + ks * 32 + koff]);
      #pragma unroll
      for (int n = 0; n < 3; ++n) {
        const int row = bn0 + 16 * n + (lane & 15);
        const int g   = ks * 4 + (lane >> 4);
        const bf16x8 b = *reinterpret_cast<const bf16x8*>(
            &lw[cur][row * BK + ((g ^ (row & 7)) * 8)]);
        #pragma unroll
        for (int m = 0; m < 4; ++m)
          acc[m][n] = __builtin_amdgcn_mfma_f32_16x16x32_bf16(a[m], b, acc[m][n], 0, 0, 0);
      }
    }
    __syncthreads();                       // protect lx/lw overwrite
  }

  // ---- epilogue: col c -> {q,k,v}, row t ----
  #pragma unroll
  for (int n = 0; n < 3; ++n) {
    const int c   = bn0 + 16 * n + (lane & 15);
    const int sel = c >> 6, h = c & 63;
    #pragma unroll
    for (int m = 0; m < 4; ++m) {
      #pragma unroll
      for (int i = 0; i < 4; ++i) {
        const int t = m0 + 16 * m + (lane >> 4) * 4 + i;
        const ushort val = f2bf(acc[m][n][i]);
        if (sel == 0)      qo[(size_t)t * HEAD + h] = val;
        else if (sel == 1) ko[(size_t)t * HEAD + h] = val;
        else {
          const int bb = t >> 10, tin = t & 1023;
          vo[((size_t)bb * HEAD + h) * SEQ + tin] = val;
        }
      }
    }
  }
  #undef LOAD_X
  #undef WRITE_LX
  #undef STAGE_W
}

// ---------------- Flash attention (unchanged from R1) ----------------
__global__ __launch_bounds__(256) void attn_kernel(
    const ushort* __restrict__ q, const ushort* __restrict__ k,
    const ushort* __restrict__ vT, float* __restrict__ out)
{
  __shared__ ushort lk[64][72];
  __shared__ ushort lv[64][72];
  __shared__ ushort lp[4][16][72];

  const int tid  = threadIdx.x;
  const int wave = tid >> 6, lane = tid & 63;
  const int b    = blockIdx.y;
  const int qt0  = blockIdx.x * 64;
  const float scale = 0.03608439182435161f;   // 768^-0.5
  const float LOG2E = 1.4426950408889634f;

  const int koff = (lane >> 4) * 8;

  const int qrow = qt0 + 16 * wave + (lane & 15);
  const bf16x8 qa0 = *reinterpret_cast<const bf16x8*>(&q[((size_t)b * SEQ + qrow) * HEAD + koff]);
  const bf16x8 qa1 = *reinterpret_cast<const bf16x8*>(&q[((size_t)b * SEQ + qrow) * HEAD + koff + 32]);

  f32x4 o[4];
  #pragma unroll
  for (int hf = 0; hf < 4; ++hf) o[hf] = (f32x4){0.f, 0.f, 0.f, 0.f};
  float m_run[4], l_run[4];
  #pragma unroll
  for (int i = 0; i < 4; ++i) { m_run[i] = -1e30f; l_run[i] = 0.f; }

  const int srow = tid >> 2, schunk = (tid & 3) * 16;
  const int ntiles = qt0 / 64 + 1;

  for (int kt = 0; kt < ntiles; ++kt) {
    const int kv0 = kt * 64;
    __syncthreads();
    {
      const uint4* sk = reinterpret_cast<const uint4*>(&k[((size_t)b * SEQ + kv0 + srow) * HEAD + schunk]);
      uint4 k0v = sk[0], k1v = sk[1];
      *reinterpret_cast<uint4*>(&lk[srow][schunk])     = k0v;
      *reinterpret_cast<uint4*>(&lk[srow][schunk + 8]) = k1v;
      const uint4* sv = reinterpret_cast<const uint4*>(&vT[((size_t)b * HEAD + srow) * SEQ + kv0 + schunk]);
      uint4 v0v = sv[0], v1v = sv[1];
      *reinterpret_cast<uint4*>(&lv[srow][schunk])     = v0v;
      *reinterpret_cast<uint4*>(&lv[srow][schunk + 8]) = v1v;
    }
    __syncthreads();

    f32x4 s[4];
    #pragma unroll
    for (int f = 0; f < 4; ++f) {
      const bf16x8 kb0 = *reinterpret_cast<const bf16x8*>(&lk[16 * f + (lane & 15)][koff]);
      const bf16x8 kb1 = *reinterpret_cast<const bf16x8*>(&lk[16 * f + (lane & 15)][koff + 32]);
      f32x4 z = (f32x4){0.f, 0.f, 0.f, 0.f};
      z    = __builtin_amdgcn_mfma_f32_16x16x32_bf16(qa0, kb0, z, 0, 0, 0);
      s[f] = __builtin_amdgcn_mfma_f32_16x16x32_bf16(qa1, kb1, z, 0, 0, 0);
    }

    const bool diag = (kv0 == qt0);
    float pv[4][4];
    float mx[4];
    #pragma unroll
    for (int i = 0; i < 4; ++i) mx[i] = -1e30f;
    #pragma unroll
    for (int f = 0; f < 4; ++f) {
      const int kvc = 16 * f + (lane & 15);
      #pragma unroll
      for (int i = 0; i < 4; ++i) {
        float val = s[f][i] * scale;
        if (diag) {
          const int qr = 16 * wave + (lane >> 4) * 4 + i;
          if (kvc > qr) val = -1e30f;
        }
        pv[f][i] = val;
        mx[i] = fmaxf(mx[i], val);
      }
    }
    #pragma unroll
    for (int i = 0; i < 4; ++i) {
      #pragma unroll
      for (int d = 1; d < 16; d <<= 1) mx[i] = fmaxf(mx[i], __shfl_xor(mx[i], d));
    }

    #pragma unroll
    for (int i = 0; i < 4; ++i) {
      const float mnew = fmaxf(m_run[i], mx[i]);
      const float resc = exp2f((m_run[i] - mnew) * LOG2E);
      m_run[i] = mnew;
      l_run[i] *= resc;
      #pragma unroll
      for (int hf = 0; hf < 4; ++hf) o[hf][i] *= resc;
      float rs = 0.f;
      #pragma unroll
      for (int f = 0; f < 4; ++f) {
        const float p = exp2f((pv[f][i] - mnew) * LOG2E);
        pv[f][i] = p;
        rs += p;
      }
      #pragma unroll
      for (int d = 1; d < 16; d <<= 1) rs += __shfl_xor(rs, d);
      l_run[i] += rs;
    }

    #pragma unroll
    for (int f = 0; f < 4; ++f) {
      #pragma unroll
      for (int i = 0; i < 4; ++i)
        lp[wave][(lane >> 4) * 4 + i][16 * f + (lane & 15)] = f2bf(pv[f][i]);
    }
    const bf16x8 pa0 = *reinterpret_cast<const bf16x8*>(&lp[wave][lane & 15][koff]);
    const bf16x8 pa1 = *reinterpret_cast<const bf16x8*>(&lp[wave][lane & 15][koff + 32]);
    #pragma unroll
    for (int hf = 0; hf < 4; ++hf) {
      const bf16x8 vb0 = *reinterpret_cast<const bf16x8*>(&lv[16 * hf + (lane & 15)][koff]);
      const bf16x8 vb1 = *reinterpret_cast<const bf16x8*>(&lv[16 * hf + (lane & 15)][koff + 32]);
      o[hf] = __builtin_amdgcn_mfma_f32_16x16x32_bf16(pa0, vb0, o[hf], 0, 0, 0);
      o[hf] = __builtin_amdgcn_mfma_f32_16x16x32_bf16(pa1, vb1, o[hf], 0, 0, 0);
    }
  }

  #pragma unroll
  for (int i = 0; i < 4; ++i) {
    const float inv = 1.0f / l_run[i];
    const int t = qt0 + 16 * wave + (lane >> 4) * 4 + i;
    #pragma unroll
    for (int hf = 0; hf < 4; ++hf) {
      out[((size_t)b * SEQ + t) * HEAD + 16 * hf + (lane & 15)] = o[hf][i] * inv;
    }
  }
}

extern "C" void kernel_launch(void* const* d_in, const int* in_sizes, int n_in,
                              void* d_out, int out_size, void* d_ws, size_t ws_size,
                              hipStream_t stream) {
  const float* x  = (const float*)d_in[0];
  const float* Wq = (const float*)d_in[1];
  const float* Wk = (const float*)d_in[2];
  const float* Wv = (const float*)d_in[3];

  ushort* qw  = (ushort*)d_ws;                         // [NT][64] bf16
  ushort* kw  = qw + (size_t)NT * HEAD;                // [NT][64] bf16
  ushort* vTw = kw + (size_t)NT * HEAD;                // [B][64][1024] bf16
  ushort* wtw = vTw + (size_t)NT * HEAD;               // [192][768] bf16 (pre-swizzled)
  float*  out = (float*)d_out;

  convw_kernel<<<(NQKV * 96) / 256, 256, 0, stream>>>(Wq, Wk, Wv, wtw);
  proj_kernel<<<NT / 64, 256, 0, stream>>>(x, wtw, qw, kw, vTw);
  attn_kernel<<<dim3(SEQ / 64, BATCH), 256, 0, stream>>>(qw, kw, vTw, out);
}

// Round 3
// 58.285 us; speedup vs baseline: 1.0528x; 1.0393x over previous
//
#include <hip/hip_runtime.h>
#include <hip/hip_bf16.h>

typedef __attribute__((ext_vector_type(8))) short bf16x8;
typedef __attribute__((ext_vector_type(4))) float f32x4;

#define BATCH 16
#define SEQ   1024
#define EMB   768
#define HEAD  64
#define NT    (BATCH*SEQ)
#define NQKV  192
#define BKP   64          // proj K-chunk
#define XS    72          // x LDS row stride (ushort) — 144B rows: conflict-free
#define WS    72          // w LDS row stride (ushort)

__device__ inline ushort f2bf(float f) {
  __hip_bfloat16 h = __float2bfloat16(f);
  return *reinterpret_cast<const ushort*>(&h);
}

// ---------- W fp32 -> bf16 (plain row-major [192][768]) ----------
__global__ __launch_bounds__(256) void convw_kernel(
    const float* __restrict__ Wq, const float* __restrict__ Wk,
    const float* __restrict__ Wv, ushort* __restrict__ wt)
{
  const int t = blockIdx.x * 256 + threadIdx.x;     // 192 rows * 96 chunks
  const int row = t / 96;
  const int gg  = t - row * 96;
  const int col = gg * 8;
  const float* W = (row < 64) ? Wq : (row < 128 ? Wk : Wv);
  const int r = row & 63;
  const float4 f0 = *reinterpret_cast<const float4*>(&W[(size_t)r * EMB + col]);
  const float4 f1 = *reinterpret_cast<const float4*>(&W[(size_t)r * EMB + col + 4]);
  union { ushort us[8]; uint4 u; } o;
  o.us[0]=f2bf(f0.x); o.us[1]=f2bf(f0.y); o.us[2]=f2bf(f0.z); o.us[3]=f2bf(f0.w);
  o.us[4]=f2bf(f1.x); o.us[5]=f2bf(f1.y); o.us[6]=f2bf(f1.z); o.us[7]=f2bf(f1.w);
  *reinterpret_cast<uint4*>(&wt[(size_t)row * EMB + col]) = o.u;
}

// ---------- fused QKV projection ----------
// grid 512 x 256 thr (4 waves). Block: M=32 rows, N=192, BK=64, 12 K-iters.
// Wave w: rows 0..31 x cols [48w,48w+48) = 2 Mfrag x 3 Nfrag.
// Reg-staged global->LDS, double-buffered, 1 barrier/iter.
__global__ __launch_bounds__(256) void proj_kernel(
    const float* __restrict__ x, const ushort* __restrict__ wt,
    ushort* __restrict__ qo, ushort* __restrict__ ko, ushort* __restrict__ vo)
{
  __shared__ ushort xs[2][32 * XS];     // 9216 B
  __shared__ ushort ws[2][NQKV * WS];   // 55296 B

  const int tid  = threadIdx.x;
  const int wave = tid >> 6, lane = tid & 63;
  const int m0   = blockIdx.x * 32;
  const int koff = (lane >> 4) * 8;
  const int bn0  = wave * 48;

  // staging coords
  const int xtr = tid >> 3;             // x row 0..31
  const int xtc = (tid & 7) * 8;        // x col (floats) 0..56
  // W chunks: c = tid + 256*j, row=c>>2, cq=(c&3)*16

  float4 xr0, xr1;
  uint4  wr[3][2];

  #define LOADX(k0_) {                                                         \
    xr0 = *reinterpret_cast<const float4*>(&x[(size_t)(m0 + xtr) * EMB + (k0_) + xtc]);     \
    xr1 = *reinterpret_cast<const float4*>(&x[(size_t)(m0 + xtr) * EMB + (k0_) + xtc + 4]); }

  #define LOADW(k0_) { _Pragma("unroll")                                       \
    for (int j = 0; j < 3; ++j) {                                              \
      const int c = tid + 256 * j, row = c >> 2, cq = (c & 3) * 16;            \
      wr[j][0] = *reinterpret_cast<const uint4*>(&wt[(size_t)row * EMB + (k0_) + cq]);      \
      wr[j][1] = *reinterpret_cast<const uint4*>(&wt[(size_t)row * EMB + (k0_) + cq + 8]); }}

  #define WRITEX(buf_) {                                                       \
    union { ushort us[8]; uint4 u; } p;                                        \
    p.us[0]=f2bf(xr0.x); p.us[1]=f2bf(xr0.y); p.us[2]=f2bf(xr0.z); p.us[3]=f2bf(xr0.w); \
    p.us[4]=f2bf(xr1.x); p.us[5]=f2bf(xr1.y); p.us[6]=f2bf(xr1.z); p.us[7]=f2bf(xr1.w); \
    *reinterpret_cast<uint4*>(&xs[buf_][xtr * XS + xtc]) = p.u; }

  #define WRITEW(buf_) { _Pragma("unroll")                                     \
    for (int j = 0; j < 3; ++j) {                                              \
      const int c = tid + 256 * j, row = c >> 2, cq = (c & 3) * 16;            \
      *reinterpret_cast<uint4*>(&ws[buf_][row * WS + cq])     = wr[j][0];      \
      *reinterpret_cast<uint4*>(&ws[buf_][row * WS + cq + 8]) = wr[j][1]; }}

  f32x4 acc[2][3];
  #pragma unroll
  for (int m = 0; m < 2; ++m)
    #pragma unroll
    for (int n = 0; n < 3; ++n) acc[m][n] = (f32x4){0.f, 0.f, 0.f, 0.f};

  LOADX(0); LOADW(0);
  WRITEX(0); WRITEW(0);

  int cur = 0;
  for (int kt = 0; kt < 12; ++kt) {
    __syncthreads();
    if (kt < 11) { LOADX((kt + 1) * BKP); LOADW((kt + 1) * BKP); }
    #pragma unroll
    for (int ks = 0; ks < 2; ++ks) {
      bf16x8 a[2];
      #pragma unroll
      for (int m = 0; m < 2; ++m)
        a[m] = *reinterpret_cast<const bf16x8*>(
            &xs[cur][(16 * m + (lane & 15)) * XS + ks * 32 + koff]);
      #pragma unroll
      for (int n = 0; n < 3; ++n) {
        const bf16x8 b = *reinterpret_cast<const bf16x8*>(
            &ws[cur][(bn0 + 16 * n + (lane & 15)) * WS + ks * 32 + koff]);
        #pragma unroll
        for (int m = 0; m < 2; ++m)
          acc[m][n] = __builtin_amdgcn_mfma_f32_16x16x32_bf16(a[m], b, acc[m][n], 0, 0, 0);
      }
    }
    if (kt < 11) { WRITEX(cur ^ 1); WRITEW(cur ^ 1); }
    cur ^= 1;
  }

  // ---- epilogue ----
  #pragma unroll
  for (int n = 0; n < 3; ++n) {
    const int c   = bn0 + 16 * n + (lane & 15);
    const int sel = c >> 6, h = c & 63;
    #pragma unroll
    for (int m = 0; m < 2; ++m) {
      #pragma unroll
      for (int i = 0; i < 4; ++i) {
        const int t = m0 + 16 * m + (lane >> 4) * 4 + i;
        const ushort val = f2bf(acc[m][n][i]);
        if (sel == 0)      qo[(size_t)t * HEAD + h] = val;
        else if (sel == 1) ko[(size_t)t * HEAD + h] = val;
        else {
          const int bb = t >> 10, tin = t & 1023;
          vo[((size_t)bb * HEAD + h) * SEQ + tin] = val;
        }
      }
    }
  }
  #undef LOADX
  #undef LOADW
  #undef WRITEX
  #undef WRITEW
}

// ---------------- Flash attention (unchanged) ----------------
__global__ __launch_bounds__(256) void attn_kernel(
    const ushort* __restrict__ q, const ushort* __restrict__ k,
    const ushort* __restrict__ vT, float* __restrict__ out)
{
  __shared__ ushort lk[64][72];
  __shared__ ushort lv[64][72];
  __shared__ ushort lp[4][16][72];

  const int tid  = threadIdx.x;
  const int wave = tid >> 6, lane = tid & 63;
  const int b    = blockIdx.y;
  const int qt0  = blockIdx.x * 64;
  const float scale = 0.03608439182435161f;   // 768^-0.5
  const float LOG2E = 1.4426950408889634f;

  const int koff = (lane >> 4) * 8;

  const int qrow = qt0 + 16 * wave + (lane & 15);
  const bf16x8 qa0 = *reinterpret_cast<const bf16x8*>(&q[((size_t)b * SEQ + qrow) * HEAD + koff]);
  const bf16x8 qa1 = *reinterpret_cast<const bf16x8*>(&q[((size_t)b * SEQ + qrow) * HEAD + koff + 32]);

  f32x4 o[4];
  #pragma unroll
  for (int hf = 0; hf < 4; ++hf) o[hf] = (f32x4){0.f, 0.f, 0.f, 0.f};
  float m_run[4], l_run[4];
  #pragma unroll
  for (int i = 0; i < 4; ++i) { m_run[i] = -1e30f; l_run[i] = 0.f; }

  const int srow = tid >> 2, schunk = (tid & 3) * 16;
  const int ntiles = qt0 / 64 + 1;

  for (int kt = 0; kt < ntiles; ++kt) {
    const int kv0 = kt * 64;
    __syncthreads();
    {
      const uint4* sk = reinterpret_cast<const uint4*>(&k[((size_t)b * SEQ + kv0 + srow) * HEAD + schunk]);
      uint4 k0v = sk[0], k1v = sk[1];
      *reinterpret_cast<uint4*>(&lk[srow][schunk])     = k0v;
      *reinterpret_cast<uint4*>(&lk[srow][schunk + 8]) = k1v;
      const uint4* sv = reinterpret_cast<const uint4*>(&vT[((size_t)b * HEAD + srow) * SEQ + kv0 + schunk]);
      uint4 v0v = sv[0], v1v = sv[1];
      *reinterpret_cast<uint4*>(&lv[srow][schunk])     = v0v;
      *reinterpret_cast<uint4*>(&lv[srow][schunk + 8]) = v1v;
    }
    __syncthreads();

    f32x4 s[4];
    #pragma unroll
    for (int f = 0; f < 4; ++f) {
      const bf16x8 kb0 = *reinterpret_cast<const bf16x8*>(&lk[16 * f + (lane & 15)][koff]);
      const bf16x8 kb1 = *reinterpret_cast<const bf16x8*>(&lk[16 * f + (lane & 15)][koff + 32]);
      f32x4 z = (f32x4){0.f, 0.f, 0.f, 0.f};
      z    = __builtin_amdgcn_mfma_f32_16x16x32_bf16(qa0, kb0, z, 0, 0, 0);
      s[f] = __builtin_amdgcn_mfma_f32_16x16x32_bf16(qa1, kb1, z, 0, 0, 0);
    }

    const bool diag = (kv0 == qt0);
    float pv[4][4];
    float mx[4];
    #pragma unroll
    for (int i = 0; i < 4; ++i) mx[i] = -1e30f;
    #pragma unroll
    for (int f = 0; f < 4; ++f) {
      const int kvc = 16 * f + (lane & 15);
      #pragma unroll
      for (int i = 0; i < 4; ++i) {
        float val = s[f][i] * scale;
        if (diag) {
          const int qr = 16 * wave + (lane >> 4) * 4 + i;
          if (kvc > qr) val = -1e30f;
        }
        pv[f][i] = val;
        mx[i] = fmaxf(mx[i], val);
      }
    }
    #pragma unroll
    for (int i = 0; i < 4; ++i) {
      #pragma unroll
      for (int d = 1; d < 16; d <<= 1) mx[i] = fmaxf(mx[i], __shfl_xor(mx[i], d));
    }

    #pragma unroll
    for (int i = 0; i < 4; ++i) {
      const float mnew = fmaxf(m_run[i], mx[i]);
      const float resc = exp2f((m_run[i] - mnew) * LOG2E);
      m_run[i] = mnew;
      l_run[i] *= resc;
      #pragma unroll
      for (int hf = 0; hf < 4; ++hf) o[hf][i] *= resc;
      float rs = 0.f;
      #pragma unroll
      for (int f = 0; f < 4; ++f) {
        const float p = exp2f((pv[f][i] - mnew) * LOG2E);
        pv[f][i] = p;
        rs += p;
      }
      #pragma unroll
      for (int d = 1; d < 16; d <<= 1) rs += __shfl_xor(rs, d);
      l_run[i] += rs;
    }

    #pragma unroll
    for (int f = 0; f < 4; ++f) {
      #pragma unroll
      for (int i = 0; i < 4; ++i)
        lp[wave][(lane >> 4) * 4 + i][16 * f + (lane & 15)] = f2bf(pv[f][i]);
    }
    const bf16x8 pa0 = *reinterpret_cast<const bf16x8*>(&lp[wave][lane & 15][koff]);
    const bf16x8 pa1 = *reinterpret_cast<const bf16x8*>(&lp[wave][lane & 15][koff + 32]);
    #pragma unroll
    for (int hf = 0; hf < 4; ++hf) {
      const bf16x8 vb0 = *reinterpret_cast<const bf16x8*>(&lv[16 * hf + (lane & 15)][koff]);
      const bf16x8 vb1 = *reinterpret_cast<const bf16x8*>(&lv[16 * hf + (lane & 15)][koff + 32]);
      o[hf] = __builtin_amdgcn_mfma_f32_16x16x32_bf16(pa0, vb0, o[hf], 0, 0, 0);
      o[hf] = __builtin_amdgcn_mfma_f32_16x16x32_bf16(pa1, vb1, o[hf], 0, 0, 0);
    }
  }

  #pragma unroll
  for (int i = 0; i < 4; ++i) {
    const float inv = 1.0f / l_run[i];
    const int t = qt0 + 16 * wave + (lane >> 4) * 4 + i;
    #pragma unroll
    for (int hf = 0; hf < 4; ++hf) {
      out[((size_t)b * SEQ + t) * HEAD + 16 * hf + (lane & 15)] = o[hf][i] * inv;
    }
  }
}

extern "C" void kernel_launch(void* const* d_in, const int* in_sizes, int n_in,
                              void* d_out, int out_size, void* d_ws, size_t ws_size,
                              hipStream_t stream) {
  const float* x  = (const float*)d_in[0];
  const float* Wq = (const float*)d_in[1];
  const float* Wk = (const float*)d_in[2];
  const float* Wv = (const float*)d_in[3];

  ushort* qw  = (ushort*)d_ws;                         // [NT][64] bf16
  ushort* kw  = qw + (size_t)NT * HEAD;                // [NT][64] bf16
  ushort* vTw = kw + (size_t)NT * HEAD;                // [B][64][1024] bf16
  ushort* wtw = vTw + (size_t)NT * HEAD;               // [192][768] bf16
  float*  out = (float*)d_out;

  convw_kernel<<<(NQKV * 96) / 256, 256, 0, stream>>>(Wq, Wk, Wv, wtw);
  proj_kernel<<<NT / 32, 256, 0, stream>>>(x, wtw, qw, kw, vTw);
  attn_kernel<<<dim3(SEQ / 64, BATCH), 256, 0, stream>>>(qw, kw, vTw, out);
}

// Round 4
// 53.385 us; speedup vs baseline: 1.1494x; 1.0918x over previous
//
#include <hip/hip_runtime.h>
#include <hip/hip_bf16.h>

typedef __attribute__((ext_vector_type(8))) short bf16x8;
typedef __attribute__((ext_vector_type(4))) float f32x4;

#define BATCH 16
#define SEQ   1024
#define EMB   768
#define HEAD  64
#define NT    (BATCH*SEQ)
#define NQKV  192
#define BKP   64          // proj K-chunk
#define XS    72          // x LDS row stride (ushort)
#define WS    72          // w LDS row stride (ushort)

__device__ inline ushort f2bf(float f) {
  __hip_bfloat16 h = __float2bfloat16(f);
  return *reinterpret_cast<const ushort*>(&h);
}

// ---------- W fp32 -> bf16 (plain row-major [192][768]) ----------
__global__ __launch_bounds__(256) void convw_kernel(
    const float* __restrict__ Wq, const float* __restrict__ Wk,
    const float* __restrict__ Wv, ushort* __restrict__ wt)
{
  const int t = blockIdx.x * 256 + threadIdx.x;
  const int row = t / 96;
  const int gg  = t - row * 96;
  const int col = gg * 8;
  const float* W = (row < 64) ? Wq : (row < 128 ? Wk : Wv);
  const int r = row & 63;
  const float4 f0 = *reinterpret_cast<const float4*>(&W[(size_t)r * EMB + col]);
  const float4 f1 = *reinterpret_cast<const float4*>(&W[(size_t)r * EMB + col + 4]);
  union { ushort us[8]; uint4 u; } o;
  o.us[0]=f2bf(f0.x); o.us[1]=f2bf(f0.y); o.us[2]=f2bf(f0.z); o.us[3]=f2bf(f0.w);
  o.us[4]=f2bf(f1.x); o.us[5]=f2bf(f1.y); o.us[6]=f2bf(f1.z); o.us[7]=f2bf(f1.w);
  *reinterpret_cast<uint4*>(&wt[(size_t)row * EMB + col]) = o.u;
}

// ---------- fused QKV projection (unchanged from R3) ----------
__global__ __launch_bounds__(256) void proj_kernel(
    const float* __restrict__ x, const ushort* __restrict__ wt,
    ushort* __restrict__ qo, ushort* __restrict__ ko, ushort* __restrict__ vo)
{
  __shared__ ushort xs[2][32 * XS];
  __shared__ ushort ws[2][NQKV * WS];

  const int tid  = threadIdx.x;
  const int wave = tid >> 6, lane = tid & 63;
  const int m0   = blockIdx.x * 32;
  const int koff = (lane >> 4) * 8;
  const int bn0  = wave * 48;

  const int xtr = tid >> 3;
  const int xtc = (tid & 7) * 8;

  float4 xr0, xr1;
  uint4  wr[3][2];

  #define LOADX(k0_) {                                                         \
    xr0 = *reinterpret_cast<const float4*>(&x[(size_t)(m0 + xtr) * EMB + (k0_) + xtc]);     \
    xr1 = *reinterpret_cast<const float4*>(&x[(size_t)(m0 + xtr) * EMB + (k0_) + xtc + 4]); }

  #define LOADW(k0_) { _Pragma("unroll")                                       \
    for (int j = 0; j < 3; ++j) {                                              \
      const int c = tid + 256 * j, row = c >> 2, cq = (c & 3) * 16;            \
      wr[j][0] = *reinterpret_cast<const uint4*>(&wt[(size_t)row * EMB + (k0_) + cq]);      \
      wr[j][1] = *reinterpret_cast<const uint4*>(&wt[(size_t)row * EMB + (k0_) + cq + 8]); }}

  #define WRITEX(buf_) {                                                       \
    union { ushort us[8]; uint4 u; } p;                                        \
    p.us[0]=f2bf(xr0.x); p.us[1]=f2bf(xr0.y); p.us[2]=f2bf(xr0.z); p.us[3]=f2bf(xr0.w); \
    p.us[4]=f2bf(xr1.x); p.us[5]=f2bf(xr1.y); p.us[6]=f2bf(xr1.z); p.us[7]=f2bf(xr1.w); \
    *reinterpret_cast<uint4*>(&xs[buf_][xtr * XS + xtc]) = p.u; }

  #define WRITEW(buf_) { _Pragma("unroll")                                     \
    for (int j = 0; j < 3; ++j) {                                              \
      const int c = tid + 256 * j, row = c >> 2, cq = (c & 3) * 16;            \
      *reinterpret_cast<uint4*>(&ws[buf_][row * WS + cq])     = wr[j][0];      \
      *reinterpret_cast<uint4*>(&ws[buf_][row * WS + cq + 8]) = wr[j][1]; }}

  f32x4 acc[2][3];
  #pragma unroll
  for (int m = 0; m < 2; ++m)
    #pragma unroll
    for (int n = 0; n < 3; ++n) acc[m][n] = (f32x4){0.f, 0.f, 0.f, 0.f};

  LOADX(0); LOADW(0);
  WRITEX(0); WRITEW(0);

  int cur = 0;
  for (int kt = 0; kt < 12; ++kt) {
    __syncthreads();
    if (kt < 11) { LOADX((kt + 1) * BKP); LOADW((kt + 1) * BKP); }
    #pragma unroll
    for (int ks = 0; ks < 2; ++ks) {
      bf16x8 a[2];
      #pragma unroll
      for (int m = 0; m < 2; ++m)
        a[m] = *reinterpret_cast<const bf16x8*>(
            &xs[cur][(16 * m + (lane & 15)) * XS + ks * 32 + koff]);
      #pragma unroll
      for (int n = 0; n < 3; ++n) {
        const bf16x8 b = *reinterpret_cast<const bf16x8*>(
            &ws[cur][(bn0 + 16 * n + (lane & 15)) * WS + ks * 32 + koff]);
        #pragma unroll
        for (int m = 0; m < 2; ++m)
          acc[m][n] = __builtin_amdgcn_mfma_f32_16x16x32_bf16(a[m], b, acc[m][n], 0, 0, 0);
      }
    }
    if (kt < 11) { WRITEX(cur ^ 1); WRITEW(cur ^ 1); }
    cur ^= 1;
  }

  #pragma unroll
  for (int n = 0; n < 3; ++n) {
    const int c   = bn0 + 16 * n + (lane & 15);
    const int sel = c >> 6, h = c & 63;
    #pragma unroll
    for (int m = 0; m < 2; ++m) {
      #pragma unroll
      for (int i = 0; i < 4; ++i) {
        const int t = m0 + 16 * m + (lane >> 4) * 4 + i;
        const ushort val = f2bf(acc[m][n][i]);
        if (sel == 0)      qo[(size_t)t * HEAD + h] = val;
        else if (sel == 1) ko[(size_t)t * HEAD + h] = val;
        else {
          const int bb = t >> 10, tin = t & 1023;
          vo[((size_t)bb * HEAD + h) * SEQ + tin] = val;
        }
      }
    }
  }
  #undef LOADX
  #undef LOADW
  #undef WRITEX
  #undef WRITEW
}

// ---------------- Flash attention v2 ----------------
// grid 1024 linear: swz -> (b, 16-row q-tile). 4 waves split KV tiles
// round-robin; no K/V LDS (direct L2 B-frag loads); in-LDS combine.
__global__ __launch_bounds__(256, 4) void attn_kernel(
    const ushort* __restrict__ q, const ushort* __restrict__ k,
    const ushort* __restrict__ vT, float* __restrict__ out)
{
  __shared__ ushort lp[4][16][72];      // per-wave P re-layout
  __shared__ float  lo[4][16][68];      // per-wave O partial
  __shared__ float  lm[4][16], ll[4][16];

  const int tid  = threadIdx.x;
  const int wave = tid >> 6, lane = tid & 63;
  const int bid  = blockIdx.x;
  const int swz  = (bid & 7) * 128 + (bid >> 3);   // XCD-contiguous: 2 batches/XCD
  const int b    = swz >> 6;
  const int qt0  = (swz & 63) * 16;
  const float scale = 0.03608439182435161f;   // 768^-0.5
  const float LOG2E = 1.4426950408889634f;

  const int col  = lane & 15;
  const int koff = (lane >> 4) * 8;

  // Q fragments (A-layout: row = col, k = koff+j)
  const size_t qb = ((size_t)b * SEQ + qt0 + col) * HEAD;
  const bf16x8 qa0 = *reinterpret_cast<const bf16x8*>(&q[qb + koff]);
  const bf16x8 qa1 = *reinterpret_cast<const bf16x8*>(&q[qb + koff + 32]);

  f32x4 o[4];
  #pragma unroll
  for (int hf = 0; hf < 4; ++hf) o[hf] = (f32x4){0.f, 0.f, 0.f, 0.f};
  float m_run[4], l_run[4];
  #pragma unroll
  for (int i = 0; i < 4; ++i) { m_run[i] = -1e30f; l_run[i] = 0.f; }

  const int T = (qt0 + 16 + 63) >> 6;   // KV tiles (64-wide) this q-tile needs

  for (int t = wave; t < T; t += 4) {
    const int kv0 = t * 64;

    // ---- S = Q K^T : B-frags straight from global (L2) ----
    f32x4 s[4];
    #pragma unroll
    for (int f = 0; f < 4; ++f) {
      const size_t kb = ((size_t)b * SEQ + kv0 + 16 * f + col) * HEAD;
      const bf16x8 kb0 = *reinterpret_cast<const bf16x8*>(&k[kb + koff]);
      const bf16x8 kb1 = *reinterpret_cast<const bf16x8*>(&k[kb + koff + 32]);
      f32x4 z = (f32x4){0.f, 0.f, 0.f, 0.f};
      z    = __builtin_amdgcn_mfma_f32_16x16x32_bf16(qa0, kb0, z, 0, 0, 0);
      s[f] = __builtin_amdgcn_mfma_f32_16x16x32_bf16(qa1, kb1, z, 0, 0, 0);
    }

    // ---- scale + causal mask (only last tile crosses the diagonal) ----
    const bool diag = (t == T - 1);
    float pv[4][4];
    float mx[4];
    #pragma unroll
    for (int i = 0; i < 4; ++i) mx[i] = -1e30f;
    #pragma unroll
    for (int f = 0; f < 4; ++f) {
      const int kvc = kv0 + 16 * f + col;
      #pragma unroll
      for (int i = 0; i < 4; ++i) {
        float val = s[f][i] * scale;
        if (diag) {
          const int qr = qt0 + (lane >> 4) * 4 + i;
          if (kvc > qr) val = -1e30f;
        }
        pv[f][i] = val;
        mx[i] = fmaxf(mx[i], val);
      }
    }
    #pragma unroll
    for (int i = 0; i < 4; ++i) {
      #pragma unroll
      for (int d = 1; d < 16; d <<= 1) mx[i] = fmaxf(mx[i], __shfl_xor(mx[i], d));
    }

    // ---- online softmax ----
    #pragma unroll
    for (int i = 0; i < 4; ++i) {
      const float mnew = fmaxf(m_run[i], mx[i]);
      const float resc = exp2f((m_run[i] - mnew) * LOG2E);
      m_run[i] = mnew;
      l_run[i] *= resc;
      #pragma unroll
      for (int hf = 0; hf < 4; ++hf) o[hf][i] *= resc;
      float rs = 0.f;
      #pragma unroll
      for (int f = 0; f < 4; ++f) {
        const float p = exp2f((pv[f][i] - mnew) * LOG2E);
        pv[f][i] = p;
        rs += p;
      }
      #pragma unroll
      for (int d = 1; d < 16; d <<= 1) rs += __shfl_xor(rs, d);
      l_run[i] += rs;
    }

    // ---- P -> per-wave LDS re-layout, then PV (V-frags from vT global) ----
    #pragma unroll
    for (int f = 0; f < 4; ++f) {
      #pragma unroll
      for (int i = 0; i < 4; ++i)
        lp[wave][(lane >> 4) * 4 + i][16 * f + col] = f2bf(pv[f][i]);
    }
    const bf16x8 pa0 = *reinterpret_cast<const bf16x8*>(&lp[wave][col][koff]);
    const bf16x8 pa1 = *reinterpret_cast<const bf16x8*>(&lp[wave][col][koff + 32]);
    #pragma unroll
    for (int hf = 0; hf < 4; ++hf) {
      const size_t vb = ((size_t)b * HEAD + 16 * hf + col) * SEQ + kv0;
      const bf16x8 vb0 = *reinterpret_cast<const bf16x8*>(&vT[vb + koff]);
      const bf16x8 vb1 = *reinterpret_cast<const bf16x8*>(&vT[vb + koff + 32]);
      o[hf] = __builtin_amdgcn_mfma_f32_16x16x32_bf16(pa0, vb0, o[hf], 0, 0, 0);
      o[hf] = __builtin_amdgcn_mfma_f32_16x16x32_bf16(pa1, vb1, o[hf], 0, 0, 0);
    }
  }

  // ---- cross-wave combine ----
  #pragma unroll
  for (int hf = 0; hf < 4; ++hf)
    #pragma unroll
    for (int i = 0; i < 4; ++i)
      lo[wave][(lane >> 4) * 4 + i][16 * hf + col] = o[hf][i];
  if (col == 0) {
    #pragma unroll
    for (int i = 0; i < 4; ++i) {
      lm[wave][(lane >> 4) * 4 + i] = m_run[i];
      ll[wave][(lane >> 4) * 4 + i] = l_run[i];
    }
  }
  __syncthreads();

  #pragma unroll
  for (int u = 0; u < 4; ++u) {
    const int idx = tid + 256 * u;
    const int r = idx >> 6, c = idx & 63;
    const float mstar = fmaxf(fmaxf(lm[0][r], lm[1][r]), fmaxf(lm[2][r], lm[3][r]));
    float num = 0.f, den = 0.f;
    #pragma unroll
    for (int w = 0; w < 4; ++w) {
      const float sc = exp2f((lm[w][r] - mstar) * LOG2E);
      num += sc * lo[w][r][c];
      den += sc * ll[w][r];
    }
    out[((size_t)b * SEQ + qt0 + r) * HEAD + c] = num / den;
  }
}

extern "C" void kernel_launch(void* const* d_in, const int* in_sizes, int n_in,
                              void* d_out, int out_size, void* d_ws, size_t ws_size,
                              hipStream_t stream) {
  const float* x  = (const float*)d_in[0];
  const float* Wq = (const float*)d_in[1];
  const float* Wk = (const float*)d_in[2];
  const float* Wv = (const float*)d_in[3];

  ushort* qw  = (ushort*)d_ws;                         // [NT][64] bf16
  ushort* kw  = qw + (size_t)NT * HEAD;                // [NT][64] bf16
  ushort* vTw = kw + (size_t)NT * HEAD;                // [B][64][1024] bf16
  ushort* wtw = vTw + (size_t)NT * HEAD;               // [192][768] bf16
  float*  out = (float*)d_out;

  convw_kernel<<<(NQKV * 96) / 256, 256, 0, stream>>>(Wq, Wk, Wv, wtw);
  proj_kernel<<<NT / 32, 256, 0, stream>>>(x, wtw, qw, kw, vTw);
  attn_kernel<<<BATCH * (SEQ / 16), 256, 0, stream>>>(qw, kw, vTw, out);
}